// Round 2
// baseline (695.168 us; speedup 1.0000x reference)
//
#include <hip/hip_runtime.h>
#include <hip/hip_bf16.h>
#include <cstdint>

#define S_  4096
#define B_  2
#define H_  8
#define HD_ 64
#define DM_ 512
#define G_  64
#define W_  256
#define SEG_ 8
#define LDT 68   // LDS leading dim (floats): 272B rows keep float4 aligned, <=2-way banks

// ---------------- projection GEMM: C[m][n] = (sum_k A[in_row(m)][k]*Wt[n][k] + bias[n])*alpha
// perm 0: identity (hidden: (B,S,D) rows)   perm 1: q/k/v (S,B,D) -> (B,S,D)
// perm 2: qg: out row m=(b*64+g) <- hidden row b*S+g
__device__ __forceinline__ int in_row_map(int m, int perm) {
    if (perm == 0) return m;
    if (perm == 1) { int b = m >> 12, s = m & 4095; return s * 2 + b; }
    { int b = m >> 6, g = m & 63; return b * S_ + g; }
}

__global__ __launch_bounds__(256) void proj_gemm(
    const float* __restrict__ A, const float* __restrict__ Wt,
    const float* __restrict__ bias, float* __restrict__ C,
    int M, float alpha, int perm)
{
    __shared__ float As[32][LDT];
    __shared__ float Bs[32][LDT];
    const int tid = threadIdx.x;
    const int m0 = blockIdx.x * 64, n0 = blockIdx.y * 64;
    const int ty = tid >> 4, tx = tid & 15;
    const int lr = tid >> 2, lc0 = (tid & 3) * 4;

    float acc[4][4] = {};
    const float* arow = A + (size_t)in_row_map(m0 + lr, perm) * DM_;
    const float* wrow = Wt + (size_t)(n0 + lr) * DM_;

    for (int k0 = 0; k0 < DM_; k0 += 32) {
        #pragma unroll
        for (int half = 0; half < 2; ++half) {
            int c = lc0 + half * 16;
            float4 av = *(const float4*)(arow + k0 + c);
            As[c + 0][lr] = av.x; As[c + 1][lr] = av.y;
            As[c + 2][lr] = av.z; As[c + 3][lr] = av.w;
            float4 wv = *(const float4*)(wrow + k0 + c);
            Bs[c + 0][lr] = wv.x; Bs[c + 1][lr] = wv.y;
            Bs[c + 2][lr] = wv.z; Bs[c + 3][lr] = wv.w;
        }
        __syncthreads();
        #pragma unroll 8
        for (int kk = 0; kk < 32; ++kk) {
            float a[4], bb[4];
            *(float4*)a  = *(const float4*)&As[kk][ty * 4];
            *(float4*)bb = *(const float4*)&Bs[kk][tx * 4];
            #pragma unroll
            for (int i = 0; i < 4; ++i)
                #pragma unroll
                for (int j = 0; j < 4; ++j)
                    acc[i][j] = fmaf(a[i], bb[j], acc[i][j]);
        }
        __syncthreads();
    }
    float bb4[4];
    *(float4*)bb4 = *(const float4*)(bias + n0 + tx * 4);
    #pragma unroll
    for (int i = 0; i < 4; ++i) {
        float o[4];
        #pragma unroll
        for (int j = 0; j < 4; ++j) o[j] = (acc[i][j] + bb4[j]) * alpha;
        *(float4*)(C + (size_t)(m0 + ty * 4 + i) * DM_ + n0 + tx * 4) = *(const float4*)o;
    }
}

// ---------------- local (banded) + sel attention, flash-style ----------------
// block: (b, h, 64 query rows starting at s0 = (blockIdx.x+1)*64)  [chunk 0 skipped: overwritten by global]
__global__ __launch_bounds__(256) void local_attn(
    const float* __restrict__ qh, const float* __restrict__ kh,
    const float* __restrict__ vh, const int* __restrict__ amask,
    float* __restrict__ out)
{
    __shared__ float Qs[64 * LDT];   // transposed: Qs[d][q]
    __shared__ float KPs[64 * LDT];  // K transposed Ks[d][p], later reused as P[p][q]
    __shared__ float Vs[64 * LDT];   // natural: Vs[p][d]
    const int tid = threadIdx.x;
    const int b = blockIdx.z, h = blockIdx.y;
    const int s0 = (blockIdx.x + 1) * 64;
    const int ty = tid >> 4, tx = tid & 15;
    const int lr = tid >> 2, lc0 = (tid & 3) * 4;

    {
        const float* qrow = qh + ((size_t)(b * S_ + s0 + lr)) * DM_ + h * HD_;
        #pragma unroll
        for (int half = 0; half < 4; ++half) {
            int c = lc0 + half * 16;
            float4 qv = *(const float4*)(qrow + c);
            Qs[(c + 0) * LDT + lr] = qv.x;
            Qs[(c + 1) * LDT + lr] = qv.y;
            Qs[(c + 2) * LDT + lr] = qv.z;
            Qs[(c + 3) * LDT + lr] = qv.w;
        }
    }
    float m_i[4], l_i[4], acc[4][4] = {};
    #pragma unroll
    for (int i = 0; i < 4; ++i) { m_i[i] = -1e30f; l_i[i] = 0.f; }

    for (int jc = 0; jc < 10; ++jc) {
        const int p0 = (jc == 0) ? 0 : (s0 - 256 + (jc - 1) * 64);
        {   // stage K (transposed) + V (natural); clamp OOB rows (scores masked later)
            int p = p0 + lr;
            int pc = p < 0 ? 0 : (p > S_ - 1 ? S_ - 1 : p);
            const float* krow = kh + ((size_t)(b * S_ + pc)) * DM_ + h * HD_;
            const float* vrow = vh + ((size_t)(b * S_ + pc)) * DM_ + h * HD_;
            #pragma unroll
            for (int half = 0; half < 4; ++half) {
                int c = lc0 + half * 16;
                float4 kv = *(const float4*)(krow + c);
                KPs[(c + 0) * LDT + lr] = kv.x;
                KPs[(c + 1) * LDT + lr] = kv.y;
                KPs[(c + 2) * LDT + lr] = kv.z;
                KPs[(c + 3) * LDT + lr] = kv.w;
                *(float4*)&Vs[lr * LDT + c] = *(const float4*)(vrow + c);
            }
        }
        __syncthreads();
        float sc[4][4] = {};
        for (int d = 0; d < HD_; ++d) {
            float a[4], kb[4];
            *(float4*)a  = *(const float4*)&Qs[d * LDT + ty * 4];
            *(float4*)kb = *(const float4*)&KPs[d * LDT + tx * 4];
            #pragma unroll
            for (int i = 0; i < 4; ++i)
                #pragma unroll
                for (int j = 0; j < 4; ++j)
                    sc[i][j] = fmaf(a[i], kb[j], sc[i][j]);
        }
        if (jc > 0) {   // band masks: invalid -> NEG (-1e9); valid global key -> -10000
            #pragma unroll
            for (int j = 0; j < 4; ++j) {
                int p = p0 + tx * 4 + j;
                bool inb = (p >= 0) && (p < S_);
                float madd = 0.f;
                if (inb && amask[b * S_ + p] != 0) madd = -10000.f;
                #pragma unroll
                for (int i = 0; i < 4; ++i) {
                    int rel = p - (s0 + ty * 4 + i);
                    if (!inb || rel < -(int)W_ || rel > (int)W_) sc[i][j] = -1e9f;
                    else sc[i][j] += madd;
                }
            }
        }
        // online softmax (per-row state replicated across the 16 tx lanes of each ty group)
        #pragma unroll
        for (int i = 0; i < 4; ++i) {
            float rm = fmaxf(fmaxf(sc[i][0], sc[i][1]), fmaxf(sc[i][2], sc[i][3]));
            rm = fmaxf(rm, __shfl_xor(rm, 1));
            rm = fmaxf(rm, __shfl_xor(rm, 2));
            rm = fmaxf(rm, __shfl_xor(rm, 4));
            rm = fmaxf(rm, __shfl_xor(rm, 8));
            float mn = fmaxf(m_i[i], rm);
            float rs = 0.f;
            #pragma unroll
            for (int j = 0; j < 4; ++j) { sc[i][j] = __expf(sc[i][j] - mn); rs += sc[i][j]; }
            rs += __shfl_xor(rs, 1); rs += __shfl_xor(rs, 2);
            rs += __shfl_xor(rs, 4); rs += __shfl_xor(rs, 8);
            float f = __expf(m_i[i] - mn);
            l_i[i] = l_i[i] * f + rs;
            m_i[i] = mn;
            #pragma unroll
            for (int j = 0; j < 4; ++j) acc[i][j] *= f;
        }
        __syncthreads();            // everyone done reading K region
        #pragma unroll
        for (int i = 0; i < 4; ++i)
            #pragma unroll
            for (int j = 0; j < 4; ++j)
                KPs[(tx * 4 + j) * LDT + ty * 4 + i] = sc[i][j];   // P[p][q]
        __syncthreads();
        for (int p = 0; p < 64; ++p) {
            float pa[4], vb[4];
            *(float4*)pa = *(const float4*)&KPs[p * LDT + ty * 4];
            *(float4*)vb = *(const float4*)&Vs[p * LDT + tx * 4];
            #pragma unroll
            for (int i = 0; i < 4; ++i)
                #pragma unroll
                for (int j = 0; j < 4; ++j)
                    acc[i][j] = fmaf(pa[i], vb[j], acc[i][j]);
        }
        __syncthreads();            // before next chunk overwrites LDS
    }
    #pragma unroll
    for (int i = 0; i < 4; ++i) {
        float inv = 1.f / l_i[i];
        float o[4];
        #pragma unroll
        for (int j = 0; j < 4; ++j) o[j] = acc[i][j] * inv;
        *(float4*)(out + ((size_t)(b * S_ + s0 + ty * 4 + i)) * DM_ + h * HD_ + tx * 4) = *(const float4*)o;
    }
}

// ---------------- global attention: 64 queries vs all S keys, segmented flash ----------------
__global__ __launch_bounds__(256) void global_attn_partial(
    const float* __restrict__ qg, const float* __restrict__ kg,
    const float* __restrict__ vg, float* __restrict__ part_m,
    float* __restrict__ part_l, float* __restrict__ part_o)
{
    __shared__ float Qs[64 * LDT];
    __shared__ float KPs[64 * LDT];
    __shared__ float Vs[64 * LDT];
    const int tid = threadIdx.x;
    const int b = blockIdx.z, h = blockIdx.y, seg = blockIdx.x;
    const int ty = tid >> 4, tx = tid & 15;
    const int lr = tid >> 2, lc0 = (tid & 3) * 4;

    {
        const float* qrow = qg + ((size_t)(b * G_ + lr)) * DM_ + h * HD_;
        #pragma unroll
        for (int half = 0; half < 4; ++half) {
            int c = lc0 + half * 16;
            float4 qv = *(const float4*)(qrow + c);
            Qs[(c + 0) * LDT + lr] = qv.x;
            Qs[(c + 1) * LDT + lr] = qv.y;
            Qs[(c + 2) * LDT + lr] = qv.z;
            Qs[(c + 3) * LDT + lr] = qv.w;
        }
    }
    float m_i[4], l_i[4], acc[4][4] = {};
    #pragma unroll
    for (int i = 0; i < 4; ++i) { m_i[i] = -1e30f; l_i[i] = 0.f; }

    for (int jc = 0; jc < 8; ++jc) {
        const int p0 = seg * 512 + jc * 64;
        {
            int p = p0 + lr;
            const float* krow = kg + ((size_t)(b * S_ + p)) * DM_ + h * HD_;
            const float* vrow = vg + ((size_t)(b * S_ + p)) * DM_ + h * HD_;
            #pragma unroll
            for (int half = 0; half < 4; ++half) {
                int c = lc0 + half * 16;
                float4 kv = *(const float4*)(krow + c);
                KPs[(c + 0) * LDT + lr] = kv.x;
                KPs[(c + 1) * LDT + lr] = kv.y;
                KPs[(c + 2) * LDT + lr] = kv.z;
                KPs[(c + 3) * LDT + lr] = kv.w;
                *(float4*)&Vs[lr * LDT + c] = *(const float4*)(vrow + c);
            }
        }
        __syncthreads();
        float sc[4][4] = {};
        for (int d = 0; d < HD_; ++d) {
            float a[4], kb[4];
            *(float4*)a  = *(const float4*)&Qs[d * LDT + ty * 4];
            *(float4*)kb = *(const float4*)&KPs[d * LDT + tx * 4];
            #pragma unroll
            for (int i = 0; i < 4; ++i)
                #pragma unroll
                for (int j = 0; j < 4; ++j)
                    sc[i][j] = fmaf(a[i], kb[j], sc[i][j]);
        }
        #pragma unroll
        for (int i = 0; i < 4; ++i) {
            float rm = fmaxf(fmaxf(sc[i][0], sc[i][1]), fmaxf(sc[i][2], sc[i][3]));
            rm = fmaxf(rm, __shfl_xor(rm, 1));
            rm = fmaxf(rm, __shfl_xor(rm, 2));
            rm = fmaxf(rm, __shfl_xor(rm, 4));
            rm = fmaxf(rm, __shfl_xor(rm, 8));
            float mn = fmaxf(m_i[i], rm);
            float rs = 0.f;
            #pragma unroll
            for (int j = 0; j < 4; ++j) { sc[i][j] = __expf(sc[i][j] - mn); rs += sc[i][j]; }
            rs += __shfl_xor(rs, 1); rs += __shfl_xor(rs, 2);
            rs += __shfl_xor(rs, 4); rs += __shfl_xor(rs, 8);
            float f = __expf(m_i[i] - mn);
            l_i[i] = l_i[i] * f + rs;
            m_i[i] = mn;
            #pragma unroll
            for (int j = 0; j < 4; ++j) acc[i][j] *= f;
        }
        __syncthreads();
        #pragma unroll
        for (int i = 0; i < 4; ++i)
            #pragma unroll
            for (int j = 0; j < 4; ++j)
                KPs[(tx * 4 + j) * LDT + ty * 4 + i] = sc[i][j];
        __syncthreads();
        for (int p = 0; p < 64; ++p) {
            float pa[4], vb[4];
            *(float4*)pa = *(const float4*)&KPs[p * LDT + ty * 4];
            *(float4*)vb = *(const float4*)&Vs[p * LDT + tx * 4];
            #pragma unroll
            for (int i = 0; i < 4; ++i)
                #pragma unroll
                for (int j = 0; j < 4; ++j)
                    acc[i][j] = fmaf(pa[i], vb[j], acc[i][j]);
        }
        __syncthreads();
    }
    const int pid = (b * H_ + h) * SEG_ + seg;
    #pragma unroll
    for (int i = 0; i < 4; ++i) {
        *(float4*)(part_o + (size_t)pid * 4096 + (ty * 4 + i) * 64 + tx * 4) = *(const float4*)acc[i];
        if (tx == 0) {
            part_m[pid * 64 + ty * 4 + i] = m_i[i];
            part_l[pid * 64 + ty * 4 + i] = l_i[i];
        }
    }
}

__global__ __launch_bounds__(256) void global_combine(
    const float* __restrict__ part_m, const float* __restrict__ part_l,
    const float* __restrict__ part_o, float* __restrict__ out)
{
    const int bh = blockIdx.x;
    const int b = bh >> 3, h = bh & 7;
    const int tid = threadIdx.x;
    const int q = tid >> 2, d0 = (tid & 3) * 16;
    float mg = -1e30f;
    for (int s = 0; s < SEG_; ++s)
        mg = fmaxf(mg, part_m[(bh * SEG_ + s) * 64 + q]);
    float lsum = 0.f, accv[16] = {};
    for (int s = 0; s < SEG_; ++s) {
        const int pid = bh * SEG_ + s;
        float w = __expf(part_m[pid * 64 + q] - mg);
        lsum += w * part_l[pid * 64 + q];
        const float* op = part_o + (size_t)pid * 4096 + q * 64 + d0;
        #pragma unroll
        for (int t = 0; t < 4; ++t) {
            float tmp[4];
            *(float4*)tmp = *(const float4*)(op + t * 4);
            #pragma unroll
            for (int u = 0; u < 4; ++u) accv[t * 4 + u] += w * tmp[u];
        }
    }
    float inv = 1.f / lsum;
    float* orow = out + ((size_t)(b * S_ + q)) * DM_ + h * HD_ + d0;
    #pragma unroll
    for (int t = 0; t < 4; ++t) {
        float o[4];
        #pragma unroll
        for (int u = 0; u < 4; ++u) o[u] = accv[t * 4 + u] * inv;
        *(float4*)(orow + t * 4) = *(const float4*)o;
    }
}

extern "C" void kernel_launch(void* const* d_in, const int* in_sizes, int n_in,
                              void* d_out, int out_size, void* d_ws, size_t ws_size,
                              hipStream_t stream) {
    const float* hidden = (const float*)d_in[0];
    const float* q  = (const float*)d_in[1];
    const float* k  = (const float*)d_in[2];
    const float* v  = (const float*)d_in[3];
    const int* amask = (const int*)d_in[4];
    const float* Wq  = (const float*)d_in[5];  const float* bq  = (const float*)d_in[6];
    const float* Wk  = (const float*)d_in[7];  const float* bk  = (const float*)d_in[8];
    const float* Wv  = (const float*)d_in[9];  const float* bv  = (const float*)d_in[10];
    const float* Wqg = (const float*)d_in[11]; const float* bqg = (const float*)d_in[12];
    const float* Wkg = (const float*)d_in[13]; const float* bkg = (const float*)d_in[14];
    const float* Wvg = (const float*)d_in[15]; const float* bvg = (const float*)d_in[16];
    float* out = (float*)d_out;
    float* ws  = (float*)d_ws;

    // Buffer aliasing to keep ws footprint ~53MB:
    //   buf0: qh   (local)  -> later kgp (global)
    //   buf1: khp  (local)  -> later vgp (global)
    //   buf2: vhp  (local only)
    // qh/khp/vhp are dead after local_attn; kg/vg projections launch after it
    // on the same stream, so the aliasing is race-free.
    const size_t NE = (size_t)B_ * S_ * DM_;   // 4194304 floats
    float* qh  = ws;
    float* khp = qh  + NE;
    float* vhp = khp + NE;
    float* kgp = qh;           // alias (after local_attn)
    float* vgp = khp;          // alias (after local_attn)
    float* qgp = vhp + NE;                       // B*G*DM = 65536
    float* pm  = qgp + (size_t)B_ * G_ * DM_;    // B*H*SEG*64
    float* pl  = pm + B_ * H_ * SEG_ * 64;
    float* po  = pl + B_ * H_ * SEG_ * 64;       // B*H*SEG*64*64

    const float scale = 0.125f;                  // 1/sqrt(HD)
    dim3 blk(256);
    dim3 gproj(128, 8);
    hipLaunchKernelGGL(proj_gemm, gproj, blk, 0, stream, q,      Wq,  bq,  qh,  B_ * S_, scale, 1);
    hipLaunchKernelGGL(proj_gemm, gproj, blk, 0, stream, k,      Wk,  bk,  khp, B_ * S_, 1.0f,  1);
    hipLaunchKernelGGL(proj_gemm, gproj, blk, 0, stream, v,      Wv,  bv,  vhp, B_ * S_, 1.0f,  1);
    hipLaunchKernelGGL(proj_gemm, dim3(2, 8), blk, 0, stream, hidden, Wqg, bqg, qgp, B_ * G_, scale, 2);

    hipLaunchKernelGGL(local_attn, dim3(63, H_, B_), blk, 0, stream, qh, khp, vhp, amask, out);

    hipLaunchKernelGGL(proj_gemm, gproj, blk, 0, stream, hidden, Wkg, bkg, kgp, B_ * S_, 1.0f,  0);
    hipLaunchKernelGGL(proj_gemm, gproj, blk, 0, stream, hidden, Wvg, bvg, vgp, B_ * S_, 1.0f,  0);

    hipLaunchKernelGGL(global_attn_partial, dim3(SEG_, H_, B_), blk, 0, stream, qgp, kgp, vgp, pm, pl, po);
    hipLaunchKernelGGL(global_combine, dim3(B_ * H_), blk, 0, stream, pm, pl, po, out);
}

// Round 3
// 436.758 us; speedup vs baseline: 1.5917x; 1.5917x over previous
//
#include <hip/hip_runtime.h>
#include <hip/hip_bf16.h>
#include <cstdint>

#define S_   4096
#define B_   2
#define H_   8
#define HD_  64
#define DM_  512
#define G_   64
#define SEG_ 8
#define LDK  72   // LDS row stride in bf16 elems: 144B -> <=2-way bank aliasing, 16B aligned

typedef __attribute__((ext_vector_type(8))) short bf8_t;   // 8 bf16 = 4 VGPR
typedef __attribute__((ext_vector_type(4))) float f4_t;
#define MFMA16(A,Bv,C) __builtin_amdgcn_mfma_f32_16x16x32_bf16((A),(Bv),(C),0,0,0)

static __device__ __forceinline__ unsigned short f2bf(float x){
    union { float f; unsigned u; } v; v.f = x;
    unsigned r = v.u + 0x7FFFu + ((v.u >> 16) & 1u);   // RNE
    return (unsigned short)(r >> 16);
}
static __device__ __forceinline__ float bf2f(unsigned short h){
    union { unsigned u; float f; } v; v.u = (unsigned)h << 16; return v.f;
}
static __device__ __forceinline__ void split16(const float* x, unsigned short* hi, unsigned short* lo){
    #pragma unroll
    for (int u=0;u<16;++u){ unsigned short h=f2bf(x[u]); hi[u]=h; lo[u]=f2bf(x[u]-bf2f(h)); }
}
static __device__ __forceinline__ float rmax16(float x){
    x=fmaxf(x,__shfl_xor(x,1)); x=fmaxf(x,__shfl_xor(x,2));
    x=fmaxf(x,__shfl_xor(x,4)); x=fmaxf(x,__shfl_xor(x,8)); return x;
}
static __device__ __forceinline__ float rsum16(float x){
    x+=__shfl_xor(x,1); x+=__shfl_xor(x,2); x+=__shfl_xor(x,4); x+=__shfl_xor(x,8); return x;
}

// perm 0: identity (hidden rows)  perm 1: (S,B,D)->(B,S,D)  perm 2: qg rows b*S+g
__device__ __forceinline__ int in_row_map(int m, int perm) {
    if (perm == 0) return m;
    if (perm == 1) { int b = m >> 12, s = m & 4095; return s * 2 + b; }
    { int b = m >> 6, g = m & 63; return b * S_ + g; }
}

// C[m][n] = (sum_k A[row(m)][k]*Wt[n][k] + bias[n]) * alpha   via bf16 hi/lo split MFMA
__global__ __launch_bounds__(256) void proj_mfma(
    const float* __restrict__ A, const float* __restrict__ Wt,
    const float* __restrict__ bias, float* __restrict__ C,
    float alpha, int perm)
{
    __shared__ unsigned short Ah[128*LDK], Al[128*LDK], Bh[128*LDK], Bl[128*LDK];
    const int tid = threadIdx.x;
    const int m0 = blockIdx.x*128, n0 = blockIdx.y*128;
    const int w = tid>>6, l = tid&63;
    const int wr = w>>1, wc = w&1;
    const int lg = l>>4, lc = l&15;
    const int srow = tid>>1, sh32 = (tid&1)*32;

    const float* arow = A + (size_t)in_row_map(m0+srow, perm)*DM_ + sh32;
    const float* wrow = Wt + (size_t)(n0+srow)*DM_ + sh32;

    f4_t acc[4][4];
    #pragma unroll
    for(int i=0;i<4;++i)
        #pragma unroll
        for(int j=0;j<4;++j) acc[i][j] = (f4_t){0.f,0.f,0.f,0.f};

    for (int k0=0;k0<DM_;k0+=64){
        float ab[32], wb[32];
        #pragma unroll
        for(int j=0;j<8;++j){
            *(float4*)&ab[j*4] = *(const float4*)(arow + k0 + j*4);
            *(float4*)&wb[j*4] = *(const float4*)(wrow + k0 + j*4);
        }
        __syncthreads();                 // prev K-step compute done before overwrite
        #pragma unroll
        for(int c=0;c<2;++c){
            unsigned short h16[16], l16[16];
            int o = srow*LDK + sh32 + c*16;
            split16(&ab[c*16], h16, l16);
            *(bf8_t*)&Ah[o]   = *(bf8_t*)&h16[0]; *(bf8_t*)&Ah[o+8] = *(bf8_t*)&h16[8];
            *(bf8_t*)&Al[o]   = *(bf8_t*)&l16[0]; *(bf8_t*)&Al[o+8] = *(bf8_t*)&l16[8];
            split16(&wb[c*16], h16, l16);
            *(bf8_t*)&Bh[o]   = *(bf8_t*)&h16[0]; *(bf8_t*)&Bh[o+8] = *(bf8_t*)&h16[8];
            *(bf8_t*)&Bl[o]   = *(bf8_t*)&l16[0]; *(bf8_t*)&Bl[o+8] = *(bf8_t*)&l16[8];
        }
        __syncthreads();
        #pragma unroll
        for(int ks=0;ks<2;++ks){
            bf8_t a_h[4], a_l[4];
            #pragma unroll
            for(int mf=0;mf<4;++mf){
                int o = (wr*64+mf*16+lc)*LDK + ks*32 + lg*8;
                a_h[mf] = *(const bf8_t*)&Ah[o];
                a_l[mf] = *(const bf8_t*)&Al[o];
            }
            #pragma unroll
            for(int nf=0;nf<4;++nf){
                int o = (wc*64+nf*16+lc)*LDK + ks*32 + lg*8;
                bf8_t b_h = *(const bf8_t*)&Bh[o];
                bf8_t b_l = *(const bf8_t*)&Bl[o];
                #pragma unroll
                for(int mf=0;mf<4;++mf){
                    acc[mf][nf] = MFMA16(a_h[mf], b_h, acc[mf][nf]);
                    acc[mf][nf] = MFMA16(a_h[mf], b_l, acc[mf][nf]);
                    acc[mf][nf] = MFMA16(a_l[mf], b_h, acc[mf][nf]);
                }
            }
        }
    }
    #pragma unroll
    for(int nf=0;nf<4;++nf){
        float bv = bias[n0 + wc*64 + nf*16 + lc];
        #pragma unroll
        for(int mf=0;mf<4;++mf)
            #pragma unroll
            for(int i=0;i<4;++i){
                int m = m0 + wr*64 + mf*16 + lg*4 + i;
                C[(size_t)m*DM_ + n0 + wc*64 + nf*16 + lc] = (acc[mf][nf][i] + bv)*alpha;
            }
    }
}

// ---------------- local (banded+sel) attention, MFMA flash ----------------
__global__ __launch_bounds__(256) void attn_local(
    const float* __restrict__ qh, const float* __restrict__ kh,
    const float* __restrict__ vh, const int* __restrict__ amask,
    float* __restrict__ out)
{
    __shared__ unsigned short Qh[64*LDK], Ql[64*LDK], Kh[64*LDK], Kl[64*LDK];
    __shared__ unsigned short Vt[64*LDK], Ps[64*LDK];
    const int tid=threadIdx.x, b=blockIdx.z, h=blockIdx.y;
    const int s0=(blockIdx.x+1)*64;          // rows 0..63 come from the global path
    const int w=tid>>6, l=tid&63, lg=l>>4, lc=l&15;
    const int srow=tid>>2, sc=(tid&3)*16;

    {   // stage Q hi/lo once
        const float* qr = qh + ((size_t)(b*S_+s0+srow))*DM_ + h*HD_ + sc;
        float qb[16];
        #pragma unroll
        for(int j=0;j<4;++j) *(float4*)&qb[j*4] = *(const float4*)(qr+j*4);
        unsigned short h16[16], l16[16];
        split16(qb,h16,l16);
        int o = srow*LDK + sc;
        *(bf8_t*)&Qh[o]=*(bf8_t*)&h16[0]; *(bf8_t*)&Qh[o+8]=*(bf8_t*)&h16[8];
        *(bf8_t*)&Ql[o]=*(bf8_t*)&l16[0]; *(bf8_t*)&Ql[o+8]=*(bf8_t*)&l16[8];
    }
    float m_i[4]={-1e30f,-1e30f,-1e30f,-1e30f}, l_i[4]={0.f,0.f,0.f,0.f};
    f4_t acc_o[4];
    #pragma unroll
    for(int nf=0;nf<4;++nf) acc_o[nf]=(f4_t){0.f,0.f,0.f,0.f};

    for(int jc=0;jc<10;++jc){
        const int p0 = (jc==0) ? 0 : (s0-256+(jc-1)*64);
        {   // stage K hi/lo + V transposed (bf16); clamp OOB rows (masked later)
            int p = p0 + srow;
            int pc = p<0?0:(p>S_-1?S_-1:p);
            const float* kr = kh + ((size_t)(b*S_+pc))*DM_ + h*HD_ + sc;
            const float* vr = vh + ((size_t)(b*S_+pc))*DM_ + h*HD_ + sc;
            float kb[16], vb[16];
            #pragma unroll
            for(int j=0;j<4;++j){
                *(float4*)&kb[j*4] = *(const float4*)(kr+j*4);
                *(float4*)&vb[j*4] = *(const float4*)(vr+j*4);
            }
            __syncthreads();             // prev chunk's LDS reads done
            unsigned short h16[16], l16[16];
            split16(kb,h16,l16);
            int o = srow*LDK + sc;
            *(bf8_t*)&Kh[o]=*(bf8_t*)&h16[0]; *(bf8_t*)&Kh[o+8]=*(bf8_t*)&h16[8];
            *(bf8_t*)&Kl[o]=*(bf8_t*)&l16[0]; *(bf8_t*)&Kl[o+8]=*(bf8_t*)&l16[8];
            #pragma unroll
            for(int j=0;j<16;++j){
                int d = sc + j;          // XOR swizzle separates the 4 d-groups' banks
                Vt[d*LDK + (srow ^ (((d>>3)&3)<<4))] = f2bf(vb[j]);
            }
        }
        __syncthreads();
        // QK^T: S = Qh*Kh + Qh*Kl + Ql*Kh  (exact to ~2^-18)
        f4_t s4[4];
        #pragma unroll
        for(int cf=0;cf<4;++cf) s4[cf]=(f4_t){0.f,0.f,0.f,0.f};
        #pragma unroll
        for(int ks=0;ks<2;++ks){
            int qo = (w*16+lc)*LDK + ks*32 + lg*8;
            bf8_t qhf=*(const bf8_t*)&Qh[qo], qlf=*(const bf8_t*)&Ql[qo];
            #pragma unroll
            for(int cf=0;cf<4;++cf){
                int ko=(cf*16+lc)*LDK + ks*32 + lg*8;
                bf8_t khf=*(const bf8_t*)&Kh[ko], klf=*(const bf8_t*)&Kl[ko];
                s4[cf]=MFMA16(qhf,khf,s4[cf]);
                s4[cf]=MFMA16(qhf,klf,s4[cf]);
                s4[cf]=MFMA16(qlf,khf,s4[cf]);
            }
        }
        if(jc>0){   // band mask: invalid -> -1e9; valid global key -> -10000
            #pragma unroll
            for(int cf=0;cf<4;++cf){
                int p = p0 + cf*16 + lc;
                bool inb = (p>=0)&&(p<S_);
                float madd = (inb && amask[b*S_+p]!=0) ? -10000.f : 0.f;
                #pragma unroll
                for(int i=0;i<4;++i){
                    int rel = p - (s0 + w*16 + lg*4 + i);
                    s4[cf][i] = (!inb || rel<-256 || rel>256) ? -1e9f : s4[cf][i]+madd;
                }
            }
        }
        // online softmax; state per q-row, replicated across 16 lanes of each lg group
        float Pv[4][4];
        #pragma unroll
        for(int i=0;i<4;++i){
            float rm = fmaxf(fmaxf(s4[0][i],s4[1][i]),fmaxf(s4[2][i],s4[3][i]));
            rm = rmax16(rm);
            float mn = fmaxf(m_i[i], rm);
            float rs = 0.f;
            #pragma unroll
            for(int cf=0;cf<4;++cf){ float e=__expf(s4[cf][i]-mn); Pv[cf][i]=e; rs+=e; }
            rs = rsum16(rs);
            float f = __expf(m_i[i]-mn);
            l_i[i] = l_i[i]*f + rs;
            m_i[i] = mn;
            #pragma unroll
            for(int nf=0;nf<4;++nf) acc_o[nf][i]*=f;
        }
        // P (bf16) -> LDS (A-fragment layout), then PV
        #pragma unroll
        for(int cf=0;cf<4;++cf)
            #pragma unroll
            for(int i=0;i<4;++i)
                Ps[(w*16+lg*4+i)*LDK + cf*16 + lc] = f2bf(Pv[cf][i]);
        __syncthreads();
        #pragma unroll
        for(int ks=0;ks<2;++ks){
            int po = (w*16+lc)*LDK + ks*32 + lg*8;
            bf8_t pf = *(const bf8_t*)&Ps[po];
            #pragma unroll
            for(int nf=0;nf<4;++nf){
                int d = nf*16+lc;
                int vo = d*LDK + ((ks*32+lg*8) ^ (((d>>3)&3)<<4));
                bf8_t vf = *(const bf8_t*)&Vt[vo];
                acc_o[nf] = MFMA16(pf, vf, acc_o[nf]);
            }
        }
    }
    #pragma unroll
    for(int i=0;i<4;++i){
        float inv = 1.f/l_i[i];
        float* orow = out + ((size_t)(b*S_ + s0 + w*16 + lg*4 + i))*DM_ + h*HD_;
        #pragma unroll
        for(int nf=0;nf<4;++nf)
            orow[nf*16+lc] = acc_o[nf][i]*inv;
    }
}

// ---------------- global attention: 64 q vs 512-key segment, MFMA flash ----------------
__global__ __launch_bounds__(256) void attn_global(
    const float* __restrict__ qg, const float* __restrict__ kg,
    const float* __restrict__ vg, float* __restrict__ part_m,
    float* __restrict__ part_l, float* __restrict__ part_o)
{
    __shared__ unsigned short Qh[64*LDK], Ql[64*LDK], Kh[64*LDK], Kl[64*LDK];
    __shared__ unsigned short Vt[64*LDK], Ps[64*LDK];
    const int tid=threadIdx.x, b=blockIdx.z, h=blockIdx.y, seg=blockIdx.x;
    const int w=tid>>6, l=tid&63, lg=l>>4, lc=l&15;
    const int srow=tid>>2, sc=(tid&3)*16;

    {
        const float* qr = qg + ((size_t)(b*G_+srow))*DM_ + h*HD_ + sc;
        float qb[16];
        #pragma unroll
        for(int j=0;j<4;++j) *(float4*)&qb[j*4] = *(const float4*)(qr+j*4);
        unsigned short h16[16], l16[16];
        split16(qb,h16,l16);
        int o = srow*LDK + sc;
        *(bf8_t*)&Qh[o]=*(bf8_t*)&h16[0]; *(bf8_t*)&Qh[o+8]=*(bf8_t*)&h16[8];
        *(bf8_t*)&Ql[o]=*(bf8_t*)&l16[0]; *(bf8_t*)&Ql[o+8]=*(bf8_t*)&l16[8];
    }
    float m_i[4]={-1e30f,-1e30f,-1e30f,-1e30f}, l_i[4]={0.f,0.f,0.f,0.f};
    f4_t acc_o[4];
    #pragma unroll
    for(int nf=0;nf<4;++nf) acc_o[nf]=(f4_t){0.f,0.f,0.f,0.f};

    for(int jc=0;jc<8;++jc){
        const int p0 = seg*512 + jc*64;
        {
            const float* kr = kg + ((size_t)(b*S_+p0+srow))*DM_ + h*HD_ + sc;
            const float* vr = vg + ((size_t)(b*S_+p0+srow))*DM_ + h*HD_ + sc;
            float kb[16], vb[16];
            #pragma unroll
            for(int j=0;j<4;++j){
                *(float4*)&kb[j*4] = *(const float4*)(kr+j*4);
                *(float4*)&vb[j*4] = *(const float4*)(vr+j*4);
            }
            __syncthreads();
            unsigned short h16[16], l16[16];
            split16(kb,h16,l16);
            int o = srow*LDK + sc;
            *(bf8_t*)&Kh[o]=*(bf8_t*)&h16[0]; *(bf8_t*)&Kh[o+8]=*(bf8_t*)&h16[8];
            *(bf8_t*)&Kl[o]=*(bf8_t*)&l16[0]; *(bf8_t*)&Kl[o+8]=*(bf8_t*)&l16[8];
            #pragma unroll
            for(int j=0;j<16;++j){
                int d = sc + j;
                Vt[d*LDK + (srow ^ (((d>>3)&3)<<4))] = f2bf(vb[j]);
            }
        }
        __syncthreads();
        f4_t s4[4];
        #pragma unroll
        for(int cf=0;cf<4;++cf) s4[cf]=(f4_t){0.f,0.f,0.f,0.f};
        #pragma unroll
        for(int ks=0;ks<2;++ks){
            int qo = (w*16+lc)*LDK + ks*32 + lg*8;
            bf8_t qhf=*(const bf8_t*)&Qh[qo], qlf=*(const bf8_t*)&Ql[qo];
            #pragma unroll
            for(int cf=0;cf<4;++cf){
                int ko=(cf*16+lc)*LDK + ks*32 + lg*8;
                bf8_t khf=*(const bf8_t*)&Kh[ko], klf=*(const bf8_t*)&Kl[ko];
                s4[cf]=MFMA16(qhf,khf,s4[cf]);
                s4[cf]=MFMA16(qhf,klf,s4[cf]);
                s4[cf]=MFMA16(qlf,khf,s4[cf]);
            }
        }
        float Pv[4][4];
        #pragma unroll
        for(int i=0;i<4;++i){
            float rm = fmaxf(fmaxf(s4[0][i],s4[1][i]),fmaxf(s4[2][i],s4[3][i]));
            rm = rmax16(rm);
            float mn = fmaxf(m_i[i], rm);
            float rs = 0.f;
            #pragma unroll
            for(int cf=0;cf<4;++cf){ float e=__expf(s4[cf][i]-mn); Pv[cf][i]=e; rs+=e; }
            rs = rsum16(rs);
            float f = __expf(m_i[i]-mn);
            l_i[i] = l_i[i]*f + rs;
            m_i[i] = mn;
            #pragma unroll
            for(int nf=0;nf<4;++nf) acc_o[nf][i]*=f;
        }
        #pragma unroll
        for(int cf=0;cf<4;++cf)
            #pragma unroll
            for(int i=0;i<4;++i)
                Ps[(w*16+lg*4+i)*LDK + cf*16 + lc] = f2bf(Pv[cf][i]);
        __syncthreads();
        #pragma unroll
        for(int ks=0;ks<2;++ks){
            int po = (w*16+lc)*LDK + ks*32 + lg*8;
            bf8_t pf = *(const bf8_t*)&Ps[po];
            #pragma unroll
            for(int nf=0;nf<4;++nf){
                int d = nf*16+lc;
                int vo = d*LDK + ((ks*32+lg*8) ^ (((d>>3)&3)<<4));
                bf8_t vf = *(const bf8_t*)&Vt[vo];
                acc_o[nf] = MFMA16(pf, vf, acc_o[nf]);
            }
        }
    }
    const int pid = (b*H_+h)*SEG_ + seg;
    #pragma unroll
    for(int i=0;i<4;++i){
        int qrl = w*16 + lg*4 + i;
        #pragma unroll
        for(int nf=0;nf<4;++nf)
            part_o[(size_t)pid*4096 + qrl*64 + nf*16 + lc] = acc_o[nf][i];
        if(lc==0){
            part_m[pid*64+qrl] = m_i[i];
            part_l[pid*64+qrl] = l_i[i];
        }
    }
}

__global__ __launch_bounds__(256) void global_combine(
    const float* __restrict__ part_m, const float* __restrict__ part_l,
    const float* __restrict__ part_o, float* __restrict__ out)
{
    const int bh = blockIdx.x;
    const int b = bh >> 3, h = bh & 7;
    const int tid = threadIdx.x;
    const int q = tid >> 2, d0 = (tid & 3) * 16;
    float mg = -1e30f;
    for (int s = 0; s < SEG_; ++s)
        mg = fmaxf(mg, part_m[(bh * SEG_ + s) * 64 + q]);
    float lsum = 0.f, accv[16] = {};
    for (int s = 0; s < SEG_; ++s) {
        const int pid = bh * SEG_ + s;
        float wgt = __expf(part_m[pid * 64 + q] - mg);
        lsum += wgt * part_l[pid * 64 + q];
        const float* op = part_o + (size_t)pid * 4096 + q * 64 + d0;
        #pragma unroll
        for (int t = 0; t < 4; ++t) {
            float tmp[4];
            *(float4*)tmp = *(const float4*)(op + t * 4);
            #pragma unroll
            for (int u = 0; u < 4; ++u) accv[t * 4 + u] += wgt * tmp[u];
        }
    }
    float inv = 1.f / lsum;
    float* orow = out + ((size_t)(b * S_ + q)) * DM_ + h * HD_ + d0;
    #pragma unroll
    for (int t = 0; t < 4; ++t) {
        float o[4];
        #pragma unroll
        for (int u = 0; u < 4; ++u) o[u] = accv[t * 4 + u] * inv;
        *(float4*)(orow + t * 4) = *(const float4*)o;
    }
}

extern "C" void kernel_launch(void* const* d_in, const int* in_sizes, int n_in,
                              void* d_out, int out_size, void* d_ws, size_t ws_size,
                              hipStream_t stream) {
    const float* hidden = (const float*)d_in[0];
    const float* q  = (const float*)d_in[1];
    const float* k  = (const float*)d_in[2];
    const float* v  = (const float*)d_in[3];
    const int* amask = (const int*)d_in[4];
    const float* Wq  = (const float*)d_in[5];  const float* bq  = (const float*)d_in[6];
    const float* Wk  = (const float*)d_in[7];  const float* bk  = (const float*)d_in[8];
    const float* Wv  = (const float*)d_in[9];  const float* bv  = (const float*)d_in[10];
    const float* Wqg = (const float*)d_in[11]; const float* bqg = (const float*)d_in[12];
    const float* Wkg = (const float*)d_in[13]; const float* bkg = (const float*)d_in[14];
    const float* Wvg = (const float*)d_in[15]; const float* bvg = (const float*)d_in[16];
    float* out = (float*)d_out;
    float* ws  = (float*)d_ws;

    // qh/khp/vhp are dead after attn_local; kg/vg projections alias them (stream-ordered).
    const size_t NE = (size_t)B_ * S_ * DM_;     // 4194304 floats
    float* qhp = ws;
    float* khp = qhp + NE;
    float* vhp = khp + NE;
    float* kgp = qhp;            // alias
    float* vgp = khp;            // alias
    float* qgp = vhp + NE;                       // B*G*DM = 65536
    float* pm  = qgp + (size_t)B_ * G_ * DM_;
    float* pl  = pm + B_ * H_ * SEG_ * 64;
    float* po  = pl + B_ * H_ * SEG_ * 64;       // 128*4096

    const float scale = 0.125f;
    dim3 blk(256);
    dim3 gproj(64, 4);
    hipLaunchKernelGGL(proj_mfma, gproj, blk, 0, stream, q,      Wq,  bq,  qhp, scale, 1);
    hipLaunchKernelGGL(proj_mfma, gproj, blk, 0, stream, k,      Wk,  bk,  khp, 1.0f,  1);
    hipLaunchKernelGGL(proj_mfma, gproj, blk, 0, stream, v,      Wv,  bv,  vhp, 1.0f,  1);
    hipLaunchKernelGGL(proj_mfma, dim3(1, 4), blk, 0, stream, hidden, Wqg, bqg, qgp, scale, 2);

    hipLaunchKernelGGL(attn_local, dim3(63, H_, B_), blk, 0, stream, qhp, khp, vhp, amask, out);

    hipLaunchKernelGGL(proj_mfma, gproj, blk, 0, stream, hidden, Wkg, bkg, kgp, 1.0f,  0);
    hipLaunchKernelGGL(proj_mfma, gproj, blk, 0, stream, hidden, Wvg, bvg, vgp, 1.0f,  0);

    hipLaunchKernelGGL(attn_global, dim3(SEG_, H_, B_), blk, 0, stream, qgp, kgp, vgp, pm, pl, po);
    hipLaunchKernelGGL(global_combine, dim3(B_ * H_), blk, 0, stream, pm, pl, po, out);
}

// Round 4
// 313.009 us; speedup vs baseline: 2.2209x; 1.3954x over previous
//
#include <hip/hip_runtime.h>
#include <hip/hip_bf16.h>
#include <cstdint>

#define S_   4096
#define B_   2
#define H_   8
#define HD_  64
#define DM_  512
#define G_   64
#define SEGN 16
#define LDK  72   // attn LDS row stride (u16): 144B rows, 16B-aligned, ~2-way banks
#define LDA  40   // proj LDS row stride (u16): 80B rows, 16B-aligned, ~2-way banks

typedef __attribute__((ext_vector_type(8))) short bf8_t;     // 8 bf16
typedef __attribute__((ext_vector_type(4))) float f4_t;
typedef __attribute__((ext_vector_type(4))) unsigned u4_t;
#define MFMA16(A,Bv,C) __builtin_amdgcn_mfma_f32_16x16x32_bf16((A),(Bv),(C),0,0,0)

static __device__ __forceinline__ unsigned short f2bf(float x){   // RNE
    union { float f; unsigned u; } v; v.f = x;
    unsigned r = v.u + 0x7FFFu + ((v.u >> 16) & 1u);
    return (unsigned short)(r >> 16);
}
static __device__ __forceinline__ float rmax16(float x){
    x=fmaxf(x,__shfl_xor(x,1)); x=fmaxf(x,__shfl_xor(x,2));
    x=fmaxf(x,__shfl_xor(x,4)); x=fmaxf(x,__shfl_xor(x,8)); return x;
}
static __device__ __forceinline__ float rsum16(float x){
    x+=__shfl_xor(x,1); x+=__shfl_xor(x,2); x+=__shfl_xor(x,4); x+=__shfl_xor(x,8); return x;
}
// pack f32 -> u32 (bf16hi<<16 | bf16lo), trunc split (residual ~2^-15 rel)
static __device__ __forceinline__ unsigned pksplit(float x){
    unsigned u = __float_as_uint(x);
    unsigned t = u & 0xFFFF0000u;
    float r = x - __uint_as_float(t);
    return t | (__float_as_uint(r) >> 16);
}

// perm 0: identity (B,S,D rows)  perm 1: (S,B,D)->(B,S,D)  perm 2: qg rows b*S+g
__device__ __forceinline__ int in_row_map(int m, int perm) {
    if (perm == 0) return m;
    if (perm == 1) { int b = m >> 12, s = m & 4095; return s * 2 + b; }
    { int b = m >> 6, g = m & 63; return b * S_ + g; }
}

// ---------------- weight split: f32 -> packed u32, 6 tensors of 512x512 ----------------
struct WsplitArgs { const float* src[6]; unsigned* dst; };
__global__ __launch_bounds__(256) void wsplit(WsplitArgs a) {
    int e0 = (blockIdx.x * 256 + threadIdx.x) * 4;     // grid sized exactly
    int g = e0 >> 18, off = e0 & 262143;
    float4 x = *(const float4*)(a.src[g] + off);
    unsigned pk[4] = { pksplit(x.x), pksplit(x.y), pksplit(x.z), pksplit(x.w) };
    *(u4_t*)(a.dst + e0) = *(u4_t*)pk;
}

// ---------------- batched projection GEMM (3 per launch) ----------------
// C[m][n] = (sum_k A[row(m)][k]*W[n][k] + bias[n]) * alpha
// mode 0: out_pk[m][512] packed-split u32   mode 1: out_t[b][h][d][S] bf16 (transposed)
struct ProjDesc {
    const float* A; const unsigned* Wpk; const float* bias;
    unsigned* out_pk; unsigned short* out_t;
    float alpha; int perm; int mode; int mtiles;
};
struct ProjBatch { ProjDesc d[3]; };

__global__ __launch_bounds__(256) void proj_batched(ProjBatch pb) {
    const ProjDesc d = pb.d[blockIdx.z];
    if ((int)blockIdx.x >= d.mtiles) return;
    __shared__ unsigned short Ah[128*LDA], Al[128*LDA], Wh[128*LDA], Wl[128*LDA];
    const int tid = threadIdx.x;
    const int m0 = blockIdx.x*128, n0 = blockIdx.y*128;
    const int w = tid>>6, l = tid&63, wr = w>>1, wc = w&1, lg = l>>4, lc = l&15;
    const int srow = tid>>1, sk = (tid&1)*16;

    const float*    arow = d.A   + (size_t)in_row_map(m0+srow, d.perm)*DM_ + sk;
    const unsigned* wrow = d.Wpk + (size_t)(n0+srow)*DM_ + sk;

    f4_t acc[4][4];
    #pragma unroll
    for(int i=0;i<4;++i)
        #pragma unroll
        for(int j=0;j<4;++j) acc[i][j] = (f4_t){0.f,0.f,0.f,0.f};

    for (int k0 = 0; k0 < DM_; k0 += 32) {
        float a[16]; unsigned wp[16];
        #pragma unroll
        for(int j=0;j<4;++j){
            *(float4*)&a[j*4] = *(const float4*)(arow + k0 + j*4);
            *(u4_t*)&wp[j*4]  = *(const u4_t*)(wrow + k0 + j*4);
        }
        __syncthreads();
        {
            unsigned hi[8], lo[8], wh8[8], wl8[8];
            #pragma unroll
            for(int j=0;j<8;++j){
                unsigned x0=__float_as_uint(a[2*j]), x1=__float_as_uint(a[2*j+1]);
                unsigned t0=x0&0xFFFF0000u, t1=x1&0xFFFF0000u;
                float r0=a[2*j]-__uint_as_float(t0), r1=a[2*j+1]-__uint_as_float(t1);
                hi[j]=(x0>>16)|t1;
                lo[j]=(__float_as_uint(r0)>>16)|(__float_as_uint(r1)&0xFFFF0000u);
                unsigned p0=wp[2*j], p1=wp[2*j+1];
                wh8[j]=(p0>>16)|(p1&0xFFFF0000u);
                wl8[j]=(p0&0xFFFFu)|(p1<<16);
            }
            int o = srow*LDA + sk;
            *(u4_t*)&Ah[o]=*(u4_t*)&hi[0];  *(u4_t*)&Ah[o+8]=*(u4_t*)&hi[4];
            *(u4_t*)&Al[o]=*(u4_t*)&lo[0];  *(u4_t*)&Al[o+8]=*(u4_t*)&lo[4];
            *(u4_t*)&Wh[o]=*(u4_t*)&wh8[0]; *(u4_t*)&Wh[o+8]=*(u4_t*)&wh8[4];
            *(u4_t*)&Wl[o]=*(u4_t*)&wl8[0]; *(u4_t*)&Wl[o+8]=*(u4_t*)&wl8[4];
        }
        __syncthreads();
        bf8_t a_h[4], a_l[4];
        #pragma unroll
        for(int mf=0;mf<4;++mf){
            int o = (wr*64+mf*16+lc)*LDA + lg*8;
            a_h[mf]=*(const bf8_t*)&Ah[o]; a_l[mf]=*(const bf8_t*)&Al[o];
        }
        #pragma unroll
        for(int nf=0;nf<4;++nf){
            int o = (wc*64+nf*16+lc)*LDA + lg*8;
            bf8_t b_h=*(const bf8_t*)&Wh[o], b_l=*(const bf8_t*)&Wl[o];
            #pragma unroll
            for(int mf=0;mf<4;++mf){
                acc[mf][nf]=MFMA16(a_h[mf],b_h,acc[mf][nf]);
                acc[mf][nf]=MFMA16(a_h[mf],b_l,acc[mf][nf]);
                acc[mf][nf]=MFMA16(a_l[mf],b_h,acc[mf][nf]);
            }
        }
    }
    if (d.mode == 0) {
        #pragma unroll
        for(int nf=0;nf<4;++nf){
            int n = n0 + wc*64 + nf*16 + lc;
            float bv = d.bias[n];
            #pragma unroll
            for(int mf=0;mf<4;++mf){
                int mb = m0 + wr*64 + mf*16 + lg*4;
                #pragma unroll
                for(int i=0;i<4;++i)
                    d.out_pk[(size_t)(mb+i)*DM_ + n] = pksplit((acc[mf][nf][i]+bv)*d.alpha);
            }
        }
    } else {
        #pragma unroll
        for(int nf=0;nf<4;++nf){
            int n = n0 + wc*64 + nf*16 + lc;
            int h = n>>6, dl = n&63;
            float bv = d.bias[n];
            #pragma unroll
            for(int mf=0;mf<4;++mf){
                int m = m0 + wr*64 + mf*16 + lg*4;
                int b = m>>12, s = m&4095;
                unsigned short q0=f2bf(acc[mf][nf][0]+bv), q1=f2bf(acc[mf][nf][1]+bv);
                unsigned short q2=f2bf(acc[mf][nf][2]+bv), q3=f2bf(acc[mf][nf][3]+bv);
                unsigned pkw[2] = { (unsigned)q0 | ((unsigned)q1<<16),
                                    (unsigned)q2 | ((unsigned)q3<<16) };
                *(uint2*)(d.out_t + ((size_t)((b*H_+h)*HD_ + dl))*S_ + s) = *(uint2*)pkw;
            }
        }
    }
}

// ---------------- local (banded+sel) attention, MFMA flash ----------------
__global__ __launch_bounds__(256) void attn_local(
    const unsigned* __restrict__ Qpk, const unsigned* __restrict__ Kpk,
    const unsigned short* __restrict__ VT, const int* __restrict__ amask,
    float* __restrict__ out)
{
    __shared__ unsigned short Kh[64*LDK], Kl[64*LDK], Vt[64*LDK], Ps[64*LDK];
    const int tid=threadIdx.x, b=blockIdx.z, h=blockIdx.y;
    const int s0=(blockIdx.x+1)*64;
    const int w=tid>>6, l=tid&63, lg=l>>4, lc=l&15;
    const int srow=tid>>2, sc=(tid&3)*16;

    bf8_t qhf[2], qlf[2];
    {
        const unsigned* qp = Qpk + ((size_t)(b*S_ + s0 + w*16 + lc))*DM_ + h*HD_;
        #pragma unroll
        for(int ks=0;ks<2;++ks){
            unsigned qw[8];
            *(u4_t*)&qw[0] = *(const u4_t*)(qp + ks*32 + lg*8);
            *(u4_t*)&qw[4] = *(const u4_t*)(qp + ks*32 + lg*8 + 4);
            unsigned h8[4], l8[4];
            #pragma unroll
            for(int j=0;j<4;++j){
                unsigned p0=qw[2*j], p1=qw[2*j+1];
                h8[j]=(p0>>16)|(p1&0xFFFF0000u);
                l8[j]=(p0&0xFFFFu)|(p1<<16);
            }
            qhf[ks]=*(bf8_t*)h8; qlf[ks]=*(bf8_t*)l8;
        }
    }
    float m_i[4]={-1e30f,-1e30f,-1e30f,-1e30f}, l_i[4]={0.f,0.f,0.f,0.f};
    f4_t acc_o[4];
    #pragma unroll
    for(int nf=0;nf<4;++nf) acc_o[nf]=(f4_t){0.f,0.f,0.f,0.f};

    for(int jc=0;jc<10;++jc){
        const int p0 = (jc==0) ? 0 : (s0-256+(jc-1)*64);
        if (p0 <= -64 || p0 >= S_) continue;      // uniform per block
        {   // stage K (hi/lo unpack) + V (copy, pre-transposed global)
            int p = p0 + srow;
            int pc = p<0?0:(p>S_-1?S_-1:p);
            const unsigned* kp = Kpk + ((size_t)(b*S_+pc))*DM_ + h*HD_ + sc;
            unsigned kw[16];
            #pragma unroll
            for(int j=0;j<4;++j) *(u4_t*)&kw[j*4] = *(const u4_t*)(kp + j*4);
            int pv = p0 + sc; pv = pv<0?0:(pv>S_-16?S_-16:pv);
            const unsigned short* vp = VT + ((size_t)((b*H_+h)*HD_ + srow))*S_ + pv;
            u4_t v0 = *(const u4_t*)vp, v1 = *(const u4_t*)(vp+8);
            __syncthreads();                        // [A] prev PV done
            unsigned kh8[8], kl8[8];
            #pragma unroll
            for(int j=0;j<8;++j){
                unsigned p0w=kw[2*j], p1w=kw[2*j+1];
                kh8[j]=(p0w>>16)|(p1w&0xFFFF0000u);
                kl8[j]=(p0w&0xFFFFu)|(p1w<<16);
            }
            int o = srow*LDK + sc;
            *(u4_t*)&Kh[o]=*(u4_t*)&kh8[0]; *(u4_t*)&Kh[o+8]=*(u4_t*)&kh8[4];
            *(u4_t*)&Kl[o]=*(u4_t*)&kl8[0]; *(u4_t*)&Kl[o+8]=*(u4_t*)&kl8[4];
            *(u4_t*)&Vt[o]=v0;              *(u4_t*)&Vt[o+8]=v1;
        }
        __syncthreads();                            // [B]
        f4_t s4[4];
        #pragma unroll
        for(int cf=0;cf<4;++cf) s4[cf]=(f4_t){0.f,0.f,0.f,0.f};
        #pragma unroll
        for(int ks=0;ks<2;++ks){
            #pragma unroll
            for(int cf=0;cf<4;++cf){
                int ko=(cf*16+lc)*LDK + ks*32 + lg*8;
                bf8_t khf=*(const bf8_t*)&Kh[ko], klf=*(const bf8_t*)&Kl[ko];
                s4[cf]=MFMA16(qhf[ks],khf,s4[cf]);
                s4[cf]=MFMA16(qhf[ks],klf,s4[cf]);
                s4[cf]=MFMA16(qlf[ks],khf,s4[cf]);
            }
        }
        if(jc>0){
            #pragma unroll
            for(int cf=0;cf<4;++cf){
                int p = p0 + cf*16 + lc;
                bool inb = (p>=0)&&(p<S_);
                float madd = (inb && amask[b*S_+p]!=0) ? -10000.f : 0.f;
                #pragma unroll
                for(int i=0;i<4;++i){
                    int rel = p - (s0 + w*16 + lg*4 + i);
                    s4[cf][i] = (!inb || rel<-256 || rel>256) ? -1e9f : s4[cf][i]+madd;
                }
            }
        }
        float Pv[4][4];
        #pragma unroll
        for(int i=0;i<4;++i){
            float rm = fmaxf(fmaxf(s4[0][i],s4[1][i]),fmaxf(s4[2][i],s4[3][i]));
            rm = rmax16(rm);
            float mn = fmaxf(m_i[i], rm);
            float rs = 0.f;
            #pragma unroll
            for(int cf=0;cf<4;++cf){ float e=__expf(s4[cf][i]-mn); Pv[cf][i]=e; rs+=e; }
            rs = rsum16(rs);
            float f = __expf(m_i[i]-mn);
            l_i[i] = l_i[i]*f + rs;
            m_i[i] = mn;
            #pragma unroll
            for(int nf=0;nf<4;++nf) acc_o[nf][i]*=f;
        }
        #pragma unroll
        for(int cf=0;cf<4;++cf)
            #pragma unroll
            for(int i=0;i<4;++i)
                Ps[(w*16+lg*4+i)*LDK + cf*16 + lc] = f2bf(Pv[cf][i]);
        __syncthreads();                            // [C]
        #pragma unroll
        for(int ks=0;ks<2;++ks){
            bf8_t pf = *(const bf8_t*)&Ps[(w*16+lc)*LDK + ks*32 + lg*8];
            #pragma unroll
            for(int nf=0;nf<4;++nf){
                bf8_t vf = *(const bf8_t*)&Vt[(nf*16+lc)*LDK + ks*32 + lg*8];
                acc_o[nf] = MFMA16(pf, vf, acc_o[nf]);
            }
        }
    }
    #pragma unroll
    for(int i=0;i<4;++i){
        float inv = 1.f/l_i[i];
        float* orow = out + ((size_t)(b*S_ + s0 + w*16 + lg*4 + i))*DM_ + h*HD_;
        #pragma unroll
        for(int nf=0;nf<4;++nf) orow[nf*16+lc] = acc_o[nf][i]*inv;
    }
}

// ---------------- global attention: 64 q vs 256-key segment ----------------
__global__ __launch_bounds__(256) void attn_global(
    const unsigned* __restrict__ QGpk, const unsigned* __restrict__ KGpk,
    const unsigned short* __restrict__ VGT, float* __restrict__ part_m,
    float* __restrict__ part_l, float* __restrict__ part_o)
{
    __shared__ unsigned short Kh[64*LDK], Kl[64*LDK], Vt[64*LDK], Ps[64*LDK];
    const int tid=threadIdx.x, b=blockIdx.z, h=blockIdx.y, seg=blockIdx.x;
    const int w=tid>>6, l=tid&63, lg=l>>4, lc=l&15;
    const int srow=tid>>2, sc=(tid&3)*16;

    bf8_t qhf[2], qlf[2];
    {
        const unsigned* qp = QGpk + ((size_t)(b*G_ + w*16 + lc))*DM_ + h*HD_;
        #pragma unroll
        for(int ks=0;ks<2;++ks){
            unsigned qw[8];
            *(u4_t*)&qw[0] = *(const u4_t*)(qp + ks*32 + lg*8);
            *(u4_t*)&qw[4] = *(const u4_t*)(qp + ks*32 + lg*8 + 4);
            unsigned h8[4], l8[4];
            #pragma unroll
            for(int j=0;j<4;++j){
                unsigned p0=qw[2*j], p1=qw[2*j+1];
                h8[j]=(p0>>16)|(p1&0xFFFF0000u);
                l8[j]=(p0&0xFFFFu)|(p1<<16);
            }
            qhf[ks]=*(bf8_t*)h8; qlf[ks]=*(bf8_t*)l8;
        }
    }
    float m_i[4]={-1e30f,-1e30f,-1e30f,-1e30f}, l_i[4]={0.f,0.f,0.f,0.f};
    f4_t acc_o[4];
    #pragma unroll
    for(int nf=0;nf<4;++nf) acc_o[nf]=(f4_t){0.f,0.f,0.f,0.f};

    for(int jc=0;jc<4;++jc){
        const int p0 = seg*256 + jc*64;
        {
            const unsigned* kp = KGpk + ((size_t)(b*S_+p0+srow))*DM_ + h*HD_ + sc;
            unsigned kw[16];
            #pragma unroll
            for(int j=0;j<4;++j) *(u4_t*)&kw[j*4] = *(const u4_t*)(kp + j*4);
            const unsigned short* vp = VGT + ((size_t)((b*H_+h)*HD_ + srow))*S_ + p0 + sc;
            u4_t v0 = *(const u4_t*)vp, v1 = *(const u4_t*)(vp+8);
            __syncthreads();
            unsigned kh8[8], kl8[8];
            #pragma unroll
            for(int j=0;j<8;++j){
                unsigned p0w=kw[2*j], p1w=kw[2*j+1];
                kh8[j]=(p0w>>16)|(p1w&0xFFFF0000u);
                kl8[j]=(p0w&0xFFFFu)|(p1w<<16);
            }
            int o = srow*LDK + sc;
            *(u4_t*)&Kh[o]=*(u4_t*)&kh8[0]; *(u4_t*)&Kh[o+8]=*(u4_t*)&kh8[4];
            *(u4_t*)&Kl[o]=*(u4_t*)&kl8[0]; *(u4_t*)&Kl[o+8]=*(u4_t*)&kl8[4];
            *(u4_t*)&Vt[o]=v0;              *(u4_t*)&Vt[o+8]=v1;
        }
        __syncthreads();
        f4_t s4[4];
        #pragma unroll
        for(int cf=0;cf<4;++cf) s4[cf]=(f4_t){0.f,0.f,0.f,0.f};
        #pragma unroll
        for(int ks=0;ks<2;++ks){
            #pragma unroll
            for(int cf=0;cf<4;++cf){
                int ko=(cf*16+lc)*LDK + ks*32 + lg*8;
                bf8_t khf=*(const bf8_t*)&Kh[ko], klf=*(const bf8_t*)&Kl[ko];
                s4[cf]=MFMA16(qhf[ks],khf,s4[cf]);
                s4[cf]=MFMA16(qhf[ks],klf,s4[cf]);
                s4[cf]=MFMA16(qlf[ks],khf,s4[cf]);
            }
        }
        float Pv[4][4];
        #pragma unroll
        for(int i=0;i<4;++i){
            float rm = fmaxf(fmaxf(s4[0][i],s4[1][i]),fmaxf(s4[2][i],s4[3][i]));
            rm = rmax16(rm);
            float mn = fmaxf(m_i[i], rm);
            float rs = 0.f;
            #pragma unroll
            for(int cf=0;cf<4;++cf){ float e=__expf(s4[cf][i]-mn); Pv[cf][i]=e; rs+=e; }
            rs = rsum16(rs);
            float f = __expf(m_i[i]-mn);
            l_i[i] = l_i[i]*f + rs;
            m_i[i] = mn;
            #pragma unroll
            for(int nf=0;nf<4;++nf) acc_o[nf][i]*=f;
        }
        #pragma unroll
        for(int cf=0;cf<4;++cf)
            #pragma unroll
            for(int i=0;i<4;++i)
                Ps[(w*16+lg*4+i)*LDK + cf*16 + lc] = f2bf(Pv[cf][i]);
        __syncthreads();
        #pragma unroll
        for(int ks=0;ks<2;++ks){
            bf8_t pf = *(const bf8_t*)&Ps[(w*16+lc)*LDK + ks*32 + lg*8];
            #pragma unroll
            for(int nf=0;nf<4;++nf){
                bf8_t vf = *(const bf8_t*)&Vt[(nf*16+lc)*LDK + ks*32 + lg*8];
                acc_o[nf] = MFMA16(pf, vf, acc_o[nf]);
            }
        }
    }
    const int pid = (b*H_+h)*SEGN + seg;
    #pragma unroll
    for(int i=0;i<4;++i){
        int qrl = w*16 + lg*4 + i;
        #pragma unroll
        for(int nf=0;nf<4;++nf)
            part_o[(size_t)pid*4096 + qrl*64 + nf*16 + lc] = acc_o[nf][i];
        if(lc==0){
            part_m[pid*64+qrl] = m_i[i];
            part_l[pid*64+qrl] = l_i[i];
        }
    }
}

__global__ __launch_bounds__(256) void global_combine(
    const float* __restrict__ part_m, const float* __restrict__ part_l,
    const float* __restrict__ part_o, float* __restrict__ out)
{
    const int bh = blockIdx.x;
    const int b = bh >> 3, h = bh & 7;
    const int tid = threadIdx.x;
    const int q = tid >> 2, d0 = (tid & 3) * 16;
    float mg = -1e30f;
    for (int s = 0; s < SEGN; ++s)
        mg = fmaxf(mg, part_m[(bh * SEGN + s) * 64 + q]);
    float lsum = 0.f, accv[16] = {};
    for (int s = 0; s < SEGN; ++s) {
        const int pid = bh * SEGN + s;
        float wgt = __expf(part_m[pid * 64 + q] - mg);
        lsum += wgt * part_l[pid * 64 + q];
        const float* op = part_o + (size_t)pid * 4096 + q * 64 + d0;
        #pragma unroll
        for (int t = 0; t < 4; ++t) {
            float tmp[4];
            *(float4*)tmp = *(const float4*)(op + t * 4);
            #pragma unroll
            for (int u = 0; u < 4; ++u) accv[t * 4 + u] += wgt * tmp[u];
        }
    }
    float inv = 1.f / lsum;
    float* orow = out + ((size_t)(b * S_ + q)) * DM_ + h * HD_ + d0;
    #pragma unroll
    for (int t = 0; t < 4; ++t) {
        float o[4];
        #pragma unroll
        for (int u = 0; u < 4; ++u) o[u] = accv[t * 4 + u] * inv;
        *(float4*)(orow + t * 4) = *(const float4*)o;
    }
}

extern "C" void kernel_launch(void* const* d_in, const int* in_sizes, int n_in,
                              void* d_out, int out_size, void* d_ws, size_t ws_size,
                              hipStream_t stream) {
    const float* hidden = (const float*)d_in[0];
    const float* q  = (const float*)d_in[1];
    const float* k  = (const float*)d_in[2];
    const float* v  = (const float*)d_in[3];
    const int* amask = (const int*)d_in[4];
    const float* Wq  = (const float*)d_in[5];  const float* bq  = (const float*)d_in[6];
    const float* Wk  = (const float*)d_in[7];  const float* bk  = (const float*)d_in[8];
    const float* Wv  = (const float*)d_in[9];  const float* bv  = (const float*)d_in[10];
    const float* Wqg = (const float*)d_in[11]; const float* bqg = (const float*)d_in[12];
    const float* Wkg = (const float*)d_in[13]; const float* bkg = (const float*)d_in[14];
    const float* Wvg = (const float*)d_in[15]; const float* bvg = (const float*)d_in[16];
    float* out = (float*)d_out;

    // ws layout (peak ~46.5MB):
    char* base = (char*)d_ws;
    unsigned* Wpk = (unsigned*)base;                         // 6 * 1MB packed weights
    unsigned* Qpk = (unsigned*)(base + 6u*1024*1024);        // 16MB
    unsigned* Kpk = Qpk + (size_t)B_*S_*DM_;                 // 16MB
    unsigned short* VT = (unsigned short*)(Kpk + (size_t)B_*S_*DM_);  // 8MB
    unsigned* QGpk = (unsigned*)(VT + (size_t)B_*H_*HD_*S_); // 256KB
    float* pm = (float*)(QGpk + B_*G_*DM_);                  // 64KB
    float* pl = pm + B_*H_*SEGN*64;                          // 64KB
    unsigned* KGpk = Qpk;                                    // alias (after attn_local)
    unsigned short* VGT = VT;                                // alias
    float* po = (float*)Kpk;                                 // alias (4MB used)

    dim3 blk(256);
    // 1) split weights (order: Wq,Wk,Wv,Wkg,Wvg,Wqg)
    WsplitArgs wa;
    wa.src[0]=Wq; wa.src[1]=Wk; wa.src[2]=Wv; wa.src[3]=Wkg; wa.src[4]=Wvg; wa.src[5]=Wqg;
    wa.dst = Wpk;
    hipLaunchKernelGGL(wsplit, dim3(1536), blk, 0, stream, wa);

    // 2) phase-1 projections: q,k,v
    ProjBatch p1;
    p1.d[0] = { q, Wpk + 0*262144, bq, Qpk, nullptr, 0.125f, 1, 0, 64 };
    p1.d[1] = { k, Wpk + 1*262144, bk, Kpk, nullptr, 1.0f,   1, 0, 64 };
    p1.d[2] = { v, Wpk + 2*262144, bv, nullptr, VT,  1.0f,   1, 1, 64 };
    hipLaunchKernelGGL(proj_batched, dim3(64,4,3), blk, 0, stream, p1);

    // 3) local attention (rows 64..4095)
    hipLaunchKernelGGL(attn_local, dim3(63, H_, B_), blk, 0, stream, Qpk, Kpk, VT, amask, out);

    // 4) phase-2 projections: kg,vg,qg (alias into Qpk/VT)
    ProjBatch p2;
    p2.d[0] = { hidden, Wpk + 3*262144, bkg, KGpk, nullptr, 1.0f,   0, 0, 64 };
    p2.d[1] = { hidden, Wpk + 4*262144, bvg, nullptr, VGT,  1.0f,   0, 1, 64 };
    p2.d[2] = { hidden, Wpk + 5*262144, bqg, QGpk, nullptr, 0.125f, 2, 0, 1  };
    hipLaunchKernelGGL(proj_batched, dim3(64,4,3), blk, 0, stream, p2);

    // 5) global attention (rows 0..63), 16 segments + combine
    hipLaunchKernelGGL(attn_global, dim3(SEGN, H_, B_), blk, 0, stream, QGpk, KGpk, VGT, pm, pl, po);
    hipLaunchKernelGGL(global_combine, dim3(B_ * H_), blk, 0, stream, pm, pl, po, out);
}